// Round 5
// baseline (561.666 us; speedup 1.0000x reference)
//
#include <hip/hip_runtime.h>

#define H_  32
#define E_  128
#define D_  512
#define B_  8
#define LQ_ 1024
#define LK_ 1024

typedef __bf16 bf16x8 __attribute__((ext_vector_type(8)));
typedef float  f32x4  __attribute__((ext_vector_type(4)));
typedef float  f32x16 __attribute__((ext_vector_type(16)));

typedef __attribute__((address_space(1))) const unsigned int guint;
typedef __attribute__((address_space(3))) unsigned int luint;

__device__ __forceinline__ f32x4 MFMA16(bf16x8 a, bf16x8 b, f32x4 c) {
    return __builtin_amdgcn_mfma_f32_16x16x32_bf16(a, b, c, 0, 0, 0);
}
__device__ __forceinline__ f32x16 MFMA32(bf16x8 a, bf16x8 b, f32x16 c) {
    return __builtin_amdgcn_mfma_f32_32x32x16_bf16(a, b, c, 0, 0, 0);
}

__device__ __forceinline__ unsigned short f2bf(float x) {  // RNE
    union { float f; unsigned u; } v; v.f = x;
    unsigned r = v.u + 0x7fffu + ((v.u >> 16) & 1u);
    return (unsigned short)(r >> 16);
}
// pack two fp32 -> bf16x2 via byte-perm (truncating; P in [0,~32], bias ~2^-9: fine)
__device__ __forceinline__ unsigned pkbf(float a, float b) {
    union { float f; unsigned u; } x, y; x.f = a; y.f = b;
    return __builtin_amdgcn_perm(y.u, x.u, 0x07060302u);
}

// ---------------------------------------------------------------- converts
__global__ void conv_scale_kernel(const float* __restrict__ in,
                                  unsigned short* __restrict__ out,
                                  long n4, float scale) {
    long i = blockIdx.x * (long)blockDim.x + threadIdx.x;
    long stride = (long)gridDim.x * blockDim.x;
    for (; i < n4; i += stride) {
        float4 v = ((const float4*)in)[i];
        union { unsigned long long u; unsigned short s[4]; } p;
        p.s[0] = f2bf(v.x * scale); p.s[1] = f2bf(v.y * scale);
        p.s[2] = f2bf(v.z * scale); p.s[3] = f2bf(v.w * scale);
        ((unsigned long long*)out)[i] = p.u;
    }
}

__global__ void transpose_bf16_kernel(const float* __restrict__ in,
                                      unsigned short* __restrict__ out,
                                      int R, int C, long inStride, long outStride) {
    in  += (long)blockIdx.z * inStride;
    out += (long)blockIdx.z * outStride;
    __shared__ float t[32][33];
    int x = threadIdx.x, y = threadIdx.y;
    int c0 = blockIdx.x * 32, r0 = blockIdx.y * 32;
    for (int i = 0; i < 32; i += 8) t[y + i][x] = in[(long)(r0 + y + i) * C + (c0 + x)];
    __syncthreads();
    for (int i = 0; i < 32; i += 8)
        out[(long)(c0 + y + i) * R + (r0 + x)] = f2bf(t[x][y + i]);
}

// ---------------------------------------------------------------- KV projection
// 256x128 tile, BK=32, 16 K-steps. Round-5: staging via global_load_lds (16B DMA)
// into LINEAR [row][32] LDS tiles, double-buffered (A 2x16KB + B 2x8KB = 48 KB).
// Chunk swizzle (rule #21, both sides): LDS slot (l&3) of row r holds global chunk
// (l&3)^((r>>1)&3); reads fetch chunk c at slot c^((r>>1)&3). Bank-start
// (r&1)*16 + slot*4 -> 8 distinct 16B slots per 8 rows = 4-way (floor for 64B rows),
// same as the old padded layout — but the reg round-trip + 3 ds_write_b128/thread/iter
// are gone. One barrier/iter: STAGE(next, buf^1) -> compute(buf) -> __syncthreads.
__global__ __launch_bounds__(512, 4) void kv_proj_kernel(
    const unsigned short* __restrict__ sb,   // [B][LK][D] bf16
    const unsigned short* __restrict__ wkt,  // [H][E][D]  bf16 (Wk^T)
    const unsigned short* __restrict__ wvt,  // [H][E][D]
    const float* __restrict__ bk, const float* __restrict__ bv,
    unsigned short* __restrict__ Kb,         // [H][B][LK][E]
    unsigned short* __restrict__ Vtb)        // [H][B][E][LK]
{
    int bid = blockIdx.x;
    const int x = bid & 7;  int s = bid >> 3;
    const int mt = s & 3;   s >>= 2;
    const int b  = s & 7;   s >>= 3;
    const int kv = s & 1;   s >>= 1;
    const int h  = s * 8 + x;                // XCD hint: h&7 = XCD

    const unsigned short* wt = kv ? wvt : wkt;
    const float* bias = kv ? bv : bk;

    __shared__ unsigned short As[2][256 * 32];   // linear, chunk-swizzled
    __shared__ unsigned short Bs[2][128 * 32];

    const int tid = threadIdx.x;
    const int wave = tid >> 6, lane = tid & 63;
    const int ln = lane & 31, hi = lane >> 5;
    const int wm = wave & 3, wn = wave >> 2;

    const unsigned short* Ag = sb + ((long)b * LK_ + mt * 256) * D_;
    const unsigned short* Bg = wt + (long)h * E_ * D_;

    // DMA source offsets (elements). Each DMA: 64 lanes x 16B = 1 KB = 16 rows.
    // A-tile 256 rows -> 16 DMAs -> 2/wave; B-tile 128 rows -> 8 DMAs -> 1/wave.
    int aoff[2], boff;
    #pragma unroll
    for (int d = 0; d < 2; d++) {
        int row = (wave * 2 + d) * 16 + (lane >> 2);
        int ch  = (lane & 3) ^ ((row >> 1) & 3);
        aoff[d] = row * D_ + ch * 8;
    }
    {
        int row = wave * 16 + (lane >> 2);
        int ch  = (lane & 3) ^ ((row >> 1) & 3);
        boff = row * D_ + ch * 8;
    }

    #define KV_STAGE(d0_, buf_)                                                     \
        do {                                                                        \
            _Pragma("unroll")                                                       \
            for (int d = 0; d < 2; d++)                                             \
                __builtin_amdgcn_global_load_lds(                                   \
                    (guint*)(Ag + aoff[d] + (d0_)),                                 \
                    (luint*)&As[buf_][(wave * 2 + d) * 512], 16, 0, 0);             \
            __builtin_amdgcn_global_load_lds(                                       \
                (guint*)(Bg + boff + (d0_)),                                        \
                (luint*)&Bs[buf_][wave * 512], 16, 0, 0);                           \
        } while (0)

    KV_STAGE(0, 0);
    __syncthreads();

    f32x16 acc[4] = {};   // [mb][nb] 2x2

    for (int it = 0; it < 16; it++) {
        const int buf = it & 1;
        if (it < 15) KV_STAGE((it + 1) * 32, buf ^ 1);

        #pragma unroll
        for (int ss = 0; ss < 2; ss++) {
            const int c = ss * 2 + hi;                 // chunk index (8 elems)
            bf16x8 af[2], bfr[2];
            #pragma unroll
            for (int mb = 0; mb < 2; mb++) {
                const int r = wm * 64 + mb * 32 + ln;
                af[mb] = *(const bf16x8*)&As[buf][r * 32 + (c ^ ((r >> 1) & 3)) * 8];
            }
            #pragma unroll
            for (int nb = 0; nb < 2; nb++) {
                const int r = wn * 64 + nb * 32 + ln;
                bfr[nb] = *(const bf16x8*)&Bs[buf][r * 32 + (c ^ ((r >> 1) & 3)) * 8];
            }
            __builtin_amdgcn_s_setprio(1);
            #pragma unroll
            for (int mb = 0; mb < 2; mb++)
                #pragma unroll
                for (int nb = 0; nb < 2; nb++)
                    acc[mb * 2 + nb] = MFMA32(af[mb], bfr[nb], acc[mb * 2 + nb]);
            __builtin_amdgcn_s_setprio(0);
        }
        __syncthreads();                               // drains DMAs; joins waves
    }

    const int row0 = mt * 256 + wm * 64;
    const int e0 = wn * 64;
    if (!kv) {
        const long base = ((long)h * B_ + b) * LK_;
        #pragma unroll
        for (int mb = 0; mb < 2; mb++)
            #pragma unroll
            for (int nb = 0; nb < 2; nb++) {
                const int e = e0 + nb * 32 + ln;
                const float be = bias[h * E_ + e];
                #pragma unroll
                for (int r = 0; r < 16; r++) {
                    int row = row0 + mb * 32 + (r & 3) + 8 * (r >> 2) + 4 * hi;
                    Kb[(base + row) * E_ + e] = f2bf(acc[mb * 2 + nb][r] + be);
                }
            }
    } else {
        const long vbase = ((long)h * B_ + b) * E_;
        #pragma unroll
        for (int mb = 0; mb < 2; mb++)
            #pragma unroll
            for (int nb = 0; nb < 2; nb++) {
                const int e = e0 + nb * 32 + ln;
                const float be = bias[h * E_ + e];
                #pragma unroll
                for (int rg = 0; rg < 4; rg++) {
                    int k0 = row0 + mb * 32 + 8 * rg + 4 * hi;
                    union { unsigned long long u; unsigned short s2[4]; } pk;
                    #pragma unroll
                    for (int j = 0; j < 4; j++)
                        pk.s2[j] = f2bf(acc[mb * 2 + nb][rg * 4 + j] + be);
                    *(unsigned long long*)&Vtb[(vbase + e) * (long)LK_ + k0] = pk.u;
                }
            }
    }
}

// ---------------------------------------------------------------- flash attention
// 4-wave blocks, Q-tile 128 (32 q/wave), K-tile 64, 16 iters.
// ROUND-2 PROVEN SCHEDULE (173 us, 78 MB fetch): Ks single-buffered (16 KB) +
// Vs double-buffered (32 KB) = 48 KB -> 3 blocks/CU. Two __syncthreads/iter:
//   QK(t) -> syncA -> STAGE K/V(t+1) -> softmax+PV(t) -> syncB.
// (Round-4's early-V + raw-barrier stretched the fetch-to-use window and
// thrashed L3: fetch 78->560 MB, 2x slower. Keep the tight window.)
// In-structure tweaks only: tree-sum, s_setprio around MFMA clusters (m191).
__global__ __launch_bounds__(256, 3) void attn_kernel(
    const unsigned short* __restrict__ qb,   // [B][LQ][E] bf16, scale*log2e folded
    const unsigned short* __restrict__ Kb,   // [H][B][LK][E]
    const unsigned short* __restrict__ Vtb,  // [H][B][E][LK]
    unsigned short* __restrict__ ctx)        // [B][LQ][H*E] bf16
{
    int bid = blockIdx.x;
    const int b = bid & 7;                   // XCD hint
    int s = bid >> 3;
    const int qt = s & 7;
    const int h  = s >> 3;

    __shared__ unsigned short Ks[64 * 128];      // swizzled: slot c holds chunk c^(row&15)
    __shared__ unsigned short Vs[2][128 * 64];   // swizzled: slot c holds chunk c^(row&7)

    const int tid = threadIdx.x;
    const int wave = tid >> 6, lane = tid & 63;
    const int ln = lane & 31, hi = lane >> 5;

    const unsigned short* Kg = Kb  + ((long)h * B_ + b) * (long)LK_ * E_;
    const unsigned short* Vg = Vtb + ((long)h * B_ + b) * (long)E_ * LK_;
    const int qrow = qt * 128 + wave * 32;

    // Q B-frags in registers: B[n=q=ln][k = es*16 + 8*hi + j]
    bf16x8 qf[8];
    #pragma unroll
    for (int s8 = 0; s8 < 8; s8++) {
        union { uint4 u; bf16x8 v; } t;
        t.u = *(const uint4*)&qb[((long)b * LQ_ + qrow + ln) * E_ + s8 * 16 + hi * 8];
        qf[s8] = t.v;
    }

    // DMA source offsets (elements), swizzled. Wave w stages 4 KB of K + 4 KB of V
    // (4 DMAs each, 1 KB per DMA = 64 lanes x 16 B, LDS dest = base + lane*16).
    int koff[4], voff[4];
    #pragma unroll
    for (int d = 0; d < 4; d++) {
        int krow = (wave * 4 + d) * 4 + (lane >> 4);          // 0..63
        int kc = (lane & 15) ^ (krow & 15);
        koff[d] = krow * E_ + kc * 8;
        int vrow = (wave * 4 + d) * 8 + (lane >> 3);          // 0..127 (e)
        int vc = (lane & 7) ^ (vrow & 7);
        voff[d] = vrow * LK_ + vc * 8;
    }

    #define STAGE_K(t_)                                                             \
        do {                                                                        \
            _Pragma("unroll")                                                       \
            for (int d = 0; d < 4; d++)                                             \
                __builtin_amdgcn_global_load_lds(                                   \
                    (guint*)(Kg + (long)(t_) * (64 * E_) + koff[d]),                \
                    (luint*)&Ks[(wave * 4 + d) * 512], 16, 0, 0);                   \
        } while (0)
    #define STAGE_V(t_, buf_)                                                       \
        do {                                                                        \
            _Pragma("unroll")                                                       \
            for (int d = 0; d < 4; d++)                                             \
                __builtin_amdgcn_global_load_lds(                                   \
                    (guint*)(Vg + (t_) * 64 + voff[d]),                             \
                    (luint*)&Vs[buf_][(wave * 4 + d) * 512], 16, 0, 0);             \
        } while (0)

    STAGE_K(0);
    STAGE_V(0, 0);
    __syncthreads();

    f32x16 O[4] = {};
    float l_run = 0.f;

    for (int t = 0; t < 16; t++) {
        const int vb = t & 1;

        // S^T = K · Q^T : 2 m-blocks of 32 k, q = ln
        f32x16 S[2] = {};
        __builtin_amdgcn_s_setprio(1);
        #pragma unroll
        for (int es = 0; es < 8; es++) {
            #pragma unroll
            for (int mb = 0; mb < 2; mb++) {
                const int row = mb * 32 + ln;
                const int cs = (es * 2 + hi) ^ (row & 15);
                bf16x8 kf = *(const bf16x8*)&Ks[row * 128 + cs * 8];
                S[mb] = MFMA32(kf, qf[es], S[mb]);
            }
        }
        __builtin_amdgcn_s_setprio(0);

        __syncthreads();                       // A: all waves done reading Ks
        if (t < 15) {
            STAGE_K(t + 1);                    // overwrite Ks (async)
            STAGE_V(t + 1, vb ^ 1);            // fill other V buffer (async)
        }

        float tsum = 0.f;
        #pragma unroll
        for (int mb = 0; mb < 2; mb++) {
            float pv[16];
            #pragma unroll
            for (int r = 0; r < 16; r++)
                pv[r] = __builtin_amdgcn_exp2f(S[mb][r]);
            // tree-sum (short dependency chain vs 16-deep serial adds)
            {
                float t0 = (pv[0]  + pv[1])  + (pv[2]  + pv[3]);
                float t1 = (pv[4]  + pv[5])  + (pv[6]  + pv[7]);
                float t2 = (pv[8]  + pv[9])  + (pv[10] + pv[11]);
                float t3 = (pv[12] + pv[13]) + (pv[14] + pv[15]);
                tsum += (t0 + t1) + (t2 + t3);
            }
            unsigned a0 = pkbf(pv[0],  pv[1]),  b0 = pkbf(pv[2],  pv[3]);
            unsigned a1 = pkbf(pv[4],  pv[5]),  b1 = pkbf(pv[6],  pv[7]);
            unsigned a2 = pkbf(pv[8],  pv[9]),  b2 = pkbf(pv[10], pv[11]);
            unsigned a3 = pkbf(pv[12], pv[13]), b3 = pkbf(pv[14], pv[15]);
            unsigned r0 = __shfl_xor(hi ? a0 : a1, 32, 64);
            unsigned r1 = __shfl_xor(hi ? b0 : b1, 32, 64);
            unsigned r2 = __shfl_xor(hi ? a2 : a3, 32, 64);
            unsigned r3 = __shfl_xor(hi ? b2 : b3, 32, 64);
            #pragma unroll
            for (int st = 0; st < 2; st++) {
                union { unsigned u[4]; bf16x8 v; } pa;
                if (st == 0) {
                    pa.u[0] = hi ? r0 : a0;  pa.u[1] = hi ? r1 : b0;
                    pa.u[2] = hi ? a1 : r0;  pa.u[3] = hi ? b1 : r1;
                } else {
                    pa.u[0] = hi ? r2 : a2;  pa.u[1] = hi ? r3 : b2;
                    pa.u[2] = hi ? a3 : r2;  pa.u[3] = hi ? b3 : r3;
                }
                __builtin_amdgcn_s_setprio(1);
                #pragma unroll
                for (int nb = 0; nb < 4; nb++) {
                    const int vrow = nb * 32 + ln;
                    const int vc = (mb * 4 + st * 2 + hi) ^ (vrow & 7);
                    bf16x8 vf = *(const bf16x8*)&Vs[vb][vrow * 64 + vc * 8];
                    O[nb] = MFMA32(pa.v, vf, O[nb]);
                }
                __builtin_amdgcn_s_setprio(0);
            }
        }
        tsum += __shfl_xor(tsum, 32, 64);
        l_run += tsum;

        __syncthreads();                       // B: drains DMAs -> K(t+1), V(t+1) landed
    }

    const float linv = 1.f / l_run;          // lane ln holds l for q = ln
    #pragma unroll
    for (int r = 0; r < 16; r++) {
        const int rowmap = (r & 3) + 8 * (r >> 2) + 4 * hi;
        float lv = __shfl(linv, rowmap, 64);
        int qg = qrow + rowmap;
        long rowbase = ((long)b * LQ_ + qg) * (H_ * E_) + h * E_;
        #pragma unroll
        for (int nb = 0; nb < 4; nb++)
            ctx[rowbase + nb * 32 + ln] = f2bf(O[nb][r] * lv);
    }
}

// ---------------------------------------------------------------- output projection
__global__ void init_out_kernel(float* __restrict__ out, const float* __restrict__ bo) {
    int i = blockIdx.x * blockDim.x + threadIdx.x;
    float4 b4 = ((const float4*)bo)[i & 31];
    ((float4*)out)[i] = b4;
}

__global__ __launch_bounds__(256) void out_proj_kernel(
    const unsigned short* __restrict__ ctx,  // [B*LQ][H*E] bf16
    const unsigned short* __restrict__ wot,  // [E][H*E] bf16 (Wo^T)
    float* __restrict__ out)                 // [B*LQ][E] fp32 (pre-init with bo)
{
    const int qt = blockIdx.x;
    const int kc = blockIdx.y;
    __shared__ unsigned short As[128 * 72];
    __shared__ unsigned short Bs[128 * 72];
    const int tid = threadIdx.x;
    const int wave = tid >> 6, lane = tid & 63;
    const int lq = lane & 15, quad = lane >> 4;
    const long kbase = (long)kc * 1024;

    f32x4 acc[2][8] = {};

    for (int d0 = 0; d0 < 1024; d0 += 64) {
        __syncthreads();
        for (int i = 0; i < 4; i++) {
            int g = i * 256 + tid;
            int row = g >> 3, cc = (g & 7) * 8;
            *(uint4*)&As[row * 72 + cc] =
                *(const uint4*)&ctx[(long)(qt * 128 + row) * (H_ * E_) + kbase + d0 + cc];
            *(uint4*)&Bs[row * 72 + cc] =
                *(const uint4*)&wot[(long)row * (H_ * E_) + kbase + d0 + cc];
        }
        __syncthreads();
        for (int ds = 0; ds < 64; ds += 32) {
            bf16x8 a0 = *(const bf16x8*)&As[(wave * 32 + lq) * 72 + ds + quad * 8];
            bf16x8 a1 = *(const bf16x8*)&As[(wave * 32 + 16 + lq) * 72 + ds + quad * 8];
            for (int et = 0; et < 8; et++) {
                bf16x8 bb = *(const bf16x8*)&Bs[(et * 16 + lq) * 72 + ds + quad * 8];
                acc[0][et] = MFMA16(a0, bb, acc[0][et]);
                acc[1][et] = MFMA16(a1, bb, acc[1][et]);
            }
        }
    }
    for (int kt = 0; kt < 2; kt++)
        for (int et = 0; et < 8; et++)
            for (int r = 0; r < 4; r++) {
                int q = qt * 128 + wave * 32 + kt * 16 + quad * 4 + r;
                int eo = et * 16 + lq;
                atomicAdd(&out[(long)q * E_ + eo], acc[kt][et][r]);
            }
}

// ---------------------------------------------------------------- launcher
extern "C" void kernel_launch(void* const* d_in, const int* in_sizes, int n_in,
                              void* d_out, int out_size, void* d_ws, size_t ws_size,
                              hipStream_t stream) {
    const float* query  = (const float*)d_in[0];
    const float* states = (const float*)d_in[1];
    const float* Wk     = (const float*)d_in[2];
    const float* bk     = (const float*)d_in[3];
    const float* Wv     = (const float*)d_in[4];
    const float* bv     = (const float*)d_in[5];
    const float* Wo     = (const float*)d_in[6];
    const float* bo     = (const float*)d_in[7];
    float* out = (float*)d_out;

    const size_t WS_QB  = 0;
    const size_t WS_SB  = WS_QB  + 2097152UL;
    const size_t WS_WKT = WS_SB  + 8388608UL;
    const size_t WS_WVT = WS_WKT + 4194304UL;
    const size_t WS_WOT = WS_WVT + 4194304UL;
    const size_t WS_KB  = WS_WOT + 1048576UL;
    const size_t WS_VTB = WS_KB  + 67108864UL;
    const size_t WS_CTX = WS_VTB + 67108864UL;
    const size_t WS_END = WS_CTX + 67108864UL;
    if (ws_size < WS_END) return;

    char* ws = (char*)d_ws;
    unsigned short* qb  = (unsigned short*)(ws + WS_QB);
    unsigned short* sb  = (unsigned short*)(ws + WS_SB);
    unsigned short* wkt = (unsigned short*)(ws + WS_WKT);
    unsigned short* wvt = (unsigned short*)(ws + WS_WVT);
    unsigned short* wot = (unsigned short*)(ws + WS_WOT);
    unsigned short* Kb  = (unsigned short*)(ws + WS_KB);
    unsigned short* Vtb = (unsigned short*)(ws + WS_VTB);
    unsigned short* ctx = (unsigned short*)(ws + WS_CTX);

    // 1/sqrt(E) * log2(e) — attention softmax runs in base-2 domain
    const float SCALE = 0.12751744f;

    conv_scale_kernel<<<512, 256, 0, stream>>>(query, qb, (long)(B_ * LQ_ * E_ / 4), SCALE);
    conv_scale_kernel<<<1024, 256, 0, stream>>>(states, sb, (long)(B_ * LK_ * D_ / 4), 1.0f);
    transpose_bf16_kernel<<<dim3(4, 16, 32), dim3(32, 8), 0, stream>>>(
        Wk, wkt, D_, E_, (long)D_ * E_, (long)D_ * E_);
    transpose_bf16_kernel<<<dim3(4, 16, 32), dim3(32, 8), 0, stream>>>(
        Wv, wvt, D_, E_, (long)D_ * E_, (long)D_ * E_);
    transpose_bf16_kernel<<<dim3(4, 128, 1), dim3(32, 8), 0, stream>>>(
        Wo, wot, H_ * E_, E_, 0L, 0L);

    kv_proj_kernel<<<2048, 512, 0, stream>>>(sb, wkt, wvt, bk, bv, Kb, Vtb);
    attn_kernel<<<2048, 256, 0, stream>>>(qb, Kb, Vtb, ctx);

    init_out_kernel<<<1024, 256, 0, stream>>>(out, bo);
    out_proj_kernel<<<dim3(64, 4), 256, 0, stream>>>(ctx, wot, out);
}

// Round 6
// 398.307 us; speedup vs baseline: 1.4101x; 1.4101x over previous
//
#include <hip/hip_runtime.h>

#define H_  32
#define E_  128
#define D_  512
#define B_  8
#define LQ_ 1024
#define LK_ 1024

typedef __bf16 bf16x8 __attribute__((ext_vector_type(8)));
typedef float  f32x4  __attribute__((ext_vector_type(4)));
typedef float  f32x16 __attribute__((ext_vector_type(16)));

typedef __attribute__((address_space(1))) const unsigned int guint;
typedef __attribute__((address_space(3))) unsigned int luint;

__device__ __forceinline__ f32x4 MFMA16(bf16x8 a, bf16x8 b, f32x4 c) {
    return __builtin_amdgcn_mfma_f32_16x16x32_bf16(a, b, c, 0, 0, 0);
}
__device__ __forceinline__ f32x16 MFMA32(bf16x8 a, bf16x8 b, f32x16 c) {
    return __builtin_amdgcn_mfma_f32_32x32x16_bf16(a, b, c, 0, 0, 0);
}

__device__ __forceinline__ unsigned short f2bf(float x) {  // RNE
    union { float f; unsigned u; } v; v.f = x;
    unsigned r = v.u + 0x7fffu + ((v.u >> 16) & 1u);
    return (unsigned short)(r >> 16);
}
// pack two fp32 -> bf16x2 via byte-perm (truncating; P in [0,~32], bias ~2^-9: fine)
__device__ __forceinline__ unsigned pkbf(float a, float b) {
    union { float f; unsigned u; } x, y; x.f = a; y.f = b;
    return __builtin_amdgcn_perm(y.u, x.u, 0x07060302u);
}

// ---------------------------------------------------------------- converts
__global__ void conv_scale_kernel(const float* __restrict__ in,
                                  unsigned short* __restrict__ out,
                                  long n4, float scale) {
    long i = blockIdx.x * (long)blockDim.x + threadIdx.x;
    long stride = (long)gridDim.x * blockDim.x;
    for (; i < n4; i += stride) {
        float4 v = ((const float4*)in)[i];
        union { unsigned long long u; unsigned short s[4]; } p;
        p.s[0] = f2bf(v.x * scale); p.s[1] = f2bf(v.y * scale);
        p.s[2] = f2bf(v.z * scale); p.s[3] = f2bf(v.w * scale);
        ((unsigned long long*)out)[i] = p.u;
    }
}

__global__ void transpose_bf16_kernel(const float* __restrict__ in,
                                      unsigned short* __restrict__ out,
                                      int R, int C, long inStride, long outStride) {
    in  += (long)blockIdx.z * inStride;
    out += (long)blockIdx.z * outStride;
    __shared__ float t[32][33];
    int x = threadIdx.x, y = threadIdx.y;
    int c0 = blockIdx.x * 32, r0 = blockIdx.y * 32;
    for (int i = 0; i < 32; i += 8) t[y + i][x] = in[(long)(r0 + y + i) * C + (c0 + x)];
    __syncthreads();
    for (int i = 0; i < 32; i += 8)
        out[(long)(c0 + y + i) * R + (r0 + x)] = f2bf(t[x][y + i]);
}

// ---------------------------------------------------------------- KV projection
// 256x128 tile, BK=32, 16 K-steps. global_load_lds (16B DMA) staging into LINEAR
// [row][32] LDS tiles, double-buffered (A 2x16KB + B 2x8KB = 48 KB). Chunk swizzle
// (rule #21, both sides): LDS slot (l&3) of row r holds global chunk (l&3)^((r>>1)&3);
// reads fetch chunk c at slot c^((r>>1)&3). Verified round 5 (absmax bit-identical).
// NOTE: no s_setprio here either — round-5 lesson: setprio near shared-cache-
// sensitive staging desyncs co-resident blocks and thrashes L2/L3.
__global__ __launch_bounds__(512, 4) void kv_proj_kernel(
    const unsigned short* __restrict__ sb,   // [B][LK][D] bf16
    const unsigned short* __restrict__ wkt,  // [H][E][D]  bf16 (Wk^T)
    const unsigned short* __restrict__ wvt,  // [H][E][D]
    const float* __restrict__ bk, const float* __restrict__ bv,
    unsigned short* __restrict__ Kb,         // [H][B][LK][E]
    unsigned short* __restrict__ Vtb)        // [H][B][E][LK]
{
    int bid = blockIdx.x;
    const int x = bid & 7;  int s = bid >> 3;
    const int mt = s & 3;   s >>= 2;
    const int b  = s & 7;   s >>= 3;
    const int kv = s & 1;   s >>= 1;
    const int h  = s * 8 + x;                // XCD hint: h&7 = XCD

    const unsigned short* wt = kv ? wvt : wkt;
    const float* bias = kv ? bv : bk;

    __shared__ unsigned short As[2][256 * 32];   // linear, chunk-swizzled
    __shared__ unsigned short Bs[2][128 * 32];

    const int tid = threadIdx.x;
    const int wave = tid >> 6, lane = tid & 63;
    const int ln = lane & 31, hi = lane >> 5;
    const int wm = wave & 3, wn = wave >> 2;

    const unsigned short* Ag = sb + ((long)b * LK_ + mt * 256) * D_;
    const unsigned short* Bg = wt + (long)h * E_ * D_;

    // DMA source offsets (elements). Each DMA: 64 lanes x 16B = 1 KB = 16 rows.
    // A-tile 256 rows -> 16 DMAs -> 2/wave; B-tile 128 rows -> 8 DMAs -> 1/wave.
    int aoff[2], boff;
    #pragma unroll
    for (int d = 0; d < 2; d++) {
        int row = (wave * 2 + d) * 16 + (lane >> 2);
        int ch  = (lane & 3) ^ ((row >> 1) & 3);
        aoff[d] = row * D_ + ch * 8;
    }
    {
        int row = wave * 16 + (lane >> 2);
        int ch  = (lane & 3) ^ ((row >> 1) & 3);
        boff = row * D_ + ch * 8;
    }

    #define KV_STAGE(d0_, buf_)                                                     \
        do {                                                                        \
            _Pragma("unroll")                                                       \
            for (int d = 0; d < 2; d++)                                             \
                __builtin_amdgcn_global_load_lds(                                   \
                    (guint*)(Ag + aoff[d] + (d0_)),                                 \
                    (luint*)&As[buf_][(wave * 2 + d) * 512], 16, 0, 0);             \
            __builtin_amdgcn_global_load_lds(                                       \
                (guint*)(Bg + boff + (d0_)),                                        \
                (luint*)&Bs[buf_][wave * 512], 16, 0, 0);                           \
        } while (0)

    KV_STAGE(0, 0);
    __syncthreads();

    f32x16 acc[4] = {};   // [mb][nb] 2x2

    for (int it = 0; it < 16; it++) {
        const int buf = it & 1;
        if (it < 15) KV_STAGE((it + 1) * 32, buf ^ 1);

        #pragma unroll
        for (int ss = 0; ss < 2; ss++) {
            const int c = ss * 2 + hi;                 // chunk index (8 elems)
            bf16x8 af[2], bfr[2];
            #pragma unroll
            for (int mb = 0; mb < 2; mb++) {
                const int r = wm * 64 + mb * 32 + ln;
                af[mb] = *(const bf16x8*)&As[buf][r * 32 + (c ^ ((r >> 1) & 3)) * 8];
            }
            #pragma unroll
            for (int nb = 0; nb < 2; nb++) {
                const int r = wn * 64 + nb * 32 + ln;
                bfr[nb] = *(const bf16x8*)&Bs[buf][r * 32 + (c ^ ((r >> 1) & 3)) * 8];
            }
            #pragma unroll
            for (int mb = 0; mb < 2; mb++)
                #pragma unroll
                for (int nb = 0; nb < 2; nb++)
                    acc[mb * 2 + nb] = MFMA32(af[mb], bfr[nb], acc[mb * 2 + nb]);
        }
        __syncthreads();                               // drains DMAs; joins waves
    }

    const int row0 = mt * 256 + wm * 64;
    const int e0 = wn * 64;
    if (!kv) {
        const long base = ((long)h * B_ + b) * LK_;
        #pragma unroll
        for (int mb = 0; mb < 2; mb++)
            #pragma unroll
            for (int nb = 0; nb < 2; nb++) {
                const int e = e0 + nb * 32 + ln;
                const float be = bias[h * E_ + e];
                #pragma unroll
                for (int r = 0; r < 16; r++) {
                    int row = row0 + mb * 32 + (r & 3) + 8 * (r >> 2) + 4 * hi;
                    Kb[(base + row) * E_ + e] = f2bf(acc[mb * 2 + nb][r] + be);
                }
            }
    } else {
        const long vbase = ((long)h * B_ + b) * E_;
        #pragma unroll
        for (int mb = 0; mb < 2; mb++)
            #pragma unroll
            for (int nb = 0; nb < 2; nb++) {
                const int e = e0 + nb * 32 + ln;
                const float be = bias[h * E_ + e];
                #pragma unroll
                for (int rg = 0; rg < 4; rg++) {
                    int k0 = row0 + mb * 32 + 8 * rg + 4 * hi;
                    union { unsigned long long u; unsigned short s2[4]; } pk;
                    #pragma unroll
                    for (int j = 0; j < 4; j++)
                        pk.s2[j] = f2bf(acc[mb * 2 + nb][rg * 4 + j] + be);
                    *(unsigned long long*)&Vtb[(vbase + e) * (long)LK_ + k0] = pk.u;
                }
            }
    }
}

// ---------------------------------------------------------------- flash attention
// EXACT round-2 kernel (173 us, 78 MB fetch, verified). 4-wave blocks, Q-tile 128,
// K-tile 64, 16 iters. Ks single-buffered + Vs double-buffered = 48 KB -> 3 blocks/CU.
// Two barriers/iter: QK(t) -> syncA -> STAGE K/V(t+1) -> softmax+PV(t) -> syncB.
// DO NOT add s_setprio here: round-4/5 showed it desyncs qt-sibling blocks'
// K/V reuse windows and thrashes L2/L3 (fetch 78 -> 553 MB, 2x slower).
__global__ __launch_bounds__(256, 3) void attn_kernel(
    const unsigned short* __restrict__ qb,   // [B][LQ][E] bf16, scale*log2e folded
    const unsigned short* __restrict__ Kb,   // [H][B][LK][E]
    const unsigned short* __restrict__ Vtb,  // [H][B][E][LK]
    unsigned short* __restrict__ ctx)        // [B][LQ][H*E] bf16
{
    int bid = blockIdx.x;
    const int b = bid & 7;                   // XCD hint
    int s = bid >> 3;
    const int qt = s & 7;
    const int h  = s >> 3;

    __shared__ unsigned short Ks[64 * 128];      // swizzled: slot c holds chunk c^(row&15)
    __shared__ unsigned short Vs[2][128 * 64];   // swizzled: slot c holds chunk c^(row&7)

    const int tid = threadIdx.x;
    const int wave = tid >> 6, lane = tid & 63;
    const int ln = lane & 31, hi = lane >> 5;

    const unsigned short* Kg = Kb  + ((long)h * B_ + b) * (long)LK_ * E_;
    const unsigned short* Vg = Vtb + ((long)h * B_ + b) * (long)E_ * LK_;
    const int qrow = qt * 128 + wave * 32;

    // Q B-frags in registers: B[n=q=ln][k = es*16 + 8*hi + j]
    bf16x8 qf[8];
    #pragma unroll
    for (int s8 = 0; s8 < 8; s8++) {
        union { uint4 u; bf16x8 v; } t;
        t.u = *(const uint4*)&qb[((long)b * LQ_ + qrow + ln) * E_ + s8 * 16 + hi * 8];
        qf[s8] = t.v;
    }

    // DMA source offsets (elements), swizzled. Wave w stages 4 KB of K + 4 KB of V
    // (4 DMAs each, 1 KB per DMA = 64 lanes x 16 B, LDS dest = base + lane*16).
    int koff[4], voff[4];
    #pragma unroll
    for (int d = 0; d < 4; d++) {
        int krow = (wave * 4 + d) * 4 + (lane >> 4);          // 0..63
        int kc = (lane & 15) ^ (krow & 15);
        koff[d] = krow * E_ + kc * 8;
        int vrow = (wave * 4 + d) * 8 + (lane >> 3);          // 0..127 (e)
        int vc = (lane & 7) ^ (vrow & 7);
        voff[d] = vrow * LK_ + vc * 8;
    }

    #define STAGE_K(t_)                                                             \
        do {                                                                        \
            _Pragma("unroll")                                                       \
            for (int d = 0; d < 4; d++)                                             \
                __builtin_amdgcn_global_load_lds(                                   \
                    (guint*)(Kg + (long)(t_) * (64 * E_) + koff[d]),                \
                    (luint*)&Ks[(wave * 4 + d) * 512], 16, 0, 0);                   \
        } while (0)
    #define STAGE_V(t_, buf_)                                                       \
        do {                                                                        \
            _Pragma("unroll")                                                       \
            for (int d = 0; d < 4; d++)                                             \
                __builtin_amdgcn_global_load_lds(                                   \
                    (guint*)(Vg + (t_) * 64 + voff[d]),                             \
                    (luint*)&Vs[buf_][(wave * 4 + d) * 512], 16, 0, 0);             \
        } while (0)

    STAGE_K(0);
    STAGE_V(0, 0);
    __syncthreads();

    f32x16 O[4] = {};
    float l_run = 0.f;

    for (int t = 0; t < 16; t++) {
        const int vb = t & 1;

        // S^T = K · Q^T : 2 m-blocks of 32 k, q = ln
        f32x16 S[2] = {};
        #pragma unroll
        for (int es = 0; es < 8; es++) {
            #pragma unroll
            for (int mb = 0; mb < 2; mb++) {
                const int row = mb * 32 + ln;
                const int cs = (es * 2 + hi) ^ (row & 15);
                bf16x8 kf = *(const bf16x8*)&Ks[row * 128 + cs * 8];
                S[mb] = MFMA32(kf, qf[es], S[mb]);
            }
        }

        __syncthreads();                       // A: all waves done reading Ks
        if (t < 15) {
            STAGE_K(t + 1);                    // overwrite Ks (async)
            STAGE_V(t + 1, vb ^ 1);            // fill other V buffer (async)
        }

        float tsum = 0.f;
        #pragma unroll
        for (int mb = 0; mb < 2; mb++) {
            float pv[16];
            #pragma unroll
            for (int r = 0; r < 16; r++) {
                pv[r] = __builtin_amdgcn_exp2f(S[mb][r]);
                tsum += pv[r];
            }
            unsigned a0 = pkbf(pv[0],  pv[1]),  b0 = pkbf(pv[2],  pv[3]);
            unsigned a1 = pkbf(pv[4],  pv[5]),  b1 = pkbf(pv[6],  pv[7]);
            unsigned a2 = pkbf(pv[8],  pv[9]),  b2 = pkbf(pv[10], pv[11]);
            unsigned a3 = pkbf(pv[12], pv[13]), b3 = pkbf(pv[14], pv[15]);
            unsigned r0 = __shfl_xor(hi ? a0 : a1, 32, 64);
            unsigned r1 = __shfl_xor(hi ? b0 : b1, 32, 64);
            unsigned r2 = __shfl_xor(hi ? a2 : a3, 32, 64);
            unsigned r3 = __shfl_xor(hi ? b2 : b3, 32, 64);
            #pragma unroll
            for (int st = 0; st < 2; st++) {
                union { unsigned u[4]; bf16x8 v; } pa;
                if (st == 0) {
                    pa.u[0] = hi ? r0 : a0;  pa.u[1] = hi ? r1 : b0;
                    pa.u[2] = hi ? a1 : r0;  pa.u[3] = hi ? b1 : r1;
                } else {
                    pa.u[0] = hi ? r2 : a2;  pa.u[1] = hi ? r3 : b2;
                    pa.u[2] = hi ? a3 : r2;  pa.u[3] = hi ? b3 : r3;
                }
                #pragma unroll
                for (int nb = 0; nb < 4; nb++) {
                    const int vrow = nb * 32 + ln;
                    const int vc = (mb * 4 + st * 2 + hi) ^ (vrow & 7);
                    bf16x8 vf = *(const bf16x8*)&Vs[vb][vrow * 64 + vc * 8];
                    O[nb] = MFMA32(pa.v, vf, O[nb]);
                }
            }
        }
        tsum += __shfl_xor(tsum, 32, 64);
        l_run += tsum;

        __syncthreads();                       // B: drains DMAs -> K(t+1), V(t+1) landed
    }

    const float linv = 1.f / l_run;          // lane ln holds l for q = ln
    #pragma unroll
    for (int r = 0; r < 16; r++) {
        const int rowmap = (r & 3) + 8 * (r >> 2) + 4 * hi;
        float lv = __shfl(linv, rowmap, 64);
        int qg = qrow + rowmap;
        long rowbase = ((long)b * LQ_ + qg) * (H_ * E_) + h * E_;
        #pragma unroll
        for (int nb = 0; nb < 4; nb++)
            ctx[rowbase + nb * 32 + ln] = f2bf(O[nb][r] * lv);
    }
}

// ---------------------------------------------------------------- output projection
__global__ void init_out_kernel(float* __restrict__ out, const float* __restrict__ bo) {
    int i = blockIdx.x * blockDim.x + threadIdx.x;
    float4 b4 = ((const float4*)bo)[i & 31];
    ((float4*)out)[i] = b4;
}

// Round-6: K split 4 -> 8 (512-wide chunks). Grid 64x8 = 512 blocks = 2 blocks/CU
// (was 1: latency-starved at 1 wave/SIMD for a ctx-streaming GEMM). Extra cost:
// one more atomic pass over the 4 MB out buffer (~1 us of BW).
__global__ __launch_bounds__(256) void out_proj_kernel(
    const unsigned short* __restrict__ ctx,  // [B*LQ][H*E] bf16
    const unsigned short* __restrict__ wot,  // [E][H*E] bf16 (Wo^T)
    float* __restrict__ out)                 // [B*LQ][E] fp32 (pre-init with bo)
{
    const int qt = blockIdx.x;
    const int kc = blockIdx.y;
    __shared__ unsigned short As[128 * 72];
    __shared__ unsigned short Bs[128 * 72];
    const int tid = threadIdx.x;
    const int wave = tid >> 6, lane = tid & 63;
    const int lq = lane & 15, quad = lane >> 4;
    const long kbase = (long)kc * 512;

    f32x4 acc[2][8] = {};

    for (int d0 = 0; d0 < 512; d0 += 64) {
        __syncthreads();
        for (int i = 0; i < 4; i++) {
            int g = i * 256 + tid;
            int row = g >> 3, cc = (g & 7) * 8;
            *(uint4*)&As[row * 72 + cc] =
                *(const uint4*)&ctx[(long)(qt * 128 + row) * (H_ * E_) + kbase + d0 + cc];
            *(uint4*)&Bs[row * 72 + cc] =
                *(const uint4*)&wot[(long)row * (H_ * E_) + kbase + d0 + cc];
        }
        __syncthreads();
        for (int ds = 0; ds < 64; ds += 32) {
            bf16x8 a0 = *(const bf16x8*)&As[(wave * 32 + lq) * 72 + ds + quad * 8];
            bf16x8 a1 = *(const bf16x8*)&As[(wave * 32 + 16 + lq) * 72 + ds + quad * 8];
            for (int et = 0; et < 8; et++) {
                bf16x8 bb = *(const bf16x8*)&Bs[(et * 16 + lq) * 72 + ds + quad * 8];
                acc[0][et] = MFMA16(a0, bb, acc[0][et]);
                acc[1][et] = MFMA16(a1, bb, acc[1][et]);
            }
        }
    }
    for (int kt = 0; kt < 2; kt++)
        for (int et = 0; et < 8; et++)
            for (int r = 0; r < 4; r++) {
                int q = qt * 128 + wave * 32 + kt * 16 + quad * 4 + r;
                int eo = et * 16 + lq;
                atomicAdd(&out[(long)q * E_ + eo], acc[kt][et][r]);
            }
}

// ---------------------------------------------------------------- launcher
extern "C" void kernel_launch(void* const* d_in, const int* in_sizes, int n_in,
                              void* d_out, int out_size, void* d_ws, size_t ws_size,
                              hipStream_t stream) {
    const float* query  = (const float*)d_in[0];
    const float* states = (const float*)d_in[1];
    const float* Wk     = (const float*)d_in[2];
    const float* bk     = (const float*)d_in[3];
    const float* Wv     = (const float*)d_in[4];
    const float* bv     = (const float*)d_in[5];
    const float* Wo     = (const float*)d_in[6];
    const float* bo     = (const float*)d_in[7];
    float* out = (float*)d_out;

    const size_t WS_QB  = 0;
    const size_t WS_SB  = WS_QB  + 2097152UL;
    const size_t WS_WKT = WS_SB  + 8388608UL;
    const size_t WS_WVT = WS_WKT + 4194304UL;
    const size_t WS_WOT = WS_WVT + 4194304UL;
    const size_t WS_KB  = WS_WOT + 1048576UL;
    const size_t WS_VTB = WS_KB  + 67108864UL;
    const size_t WS_CTX = WS_VTB + 67108864UL;
    const size_t WS_END = WS_CTX + 67108864UL;
    if (ws_size < WS_END) return;

    char* ws = (char*)d_ws;
    unsigned short* qb  = (unsigned short*)(ws + WS_QB);
    unsigned short* sb  = (unsigned short*)(ws + WS_SB);
    unsigned short* wkt = (unsigned short*)(ws + WS_WKT);
    unsigned short* wvt = (unsigned short*)(ws + WS_WVT);
    unsigned short* wot = (unsigned short*)(ws + WS_WOT);
    unsigned short* Kb  = (unsigned short*)(ws + WS_KB);
    unsigned short* Vtb = (unsigned short*)(ws + WS_VTB);
    unsigned short* ctx = (unsigned short*)(ws + WS_CTX);

    // 1/sqrt(E) * log2(e) — attention softmax runs in base-2 domain
    const float SCALE = 0.12751744f;

    conv_scale_kernel<<<512, 256, 0, stream>>>(query, qb, (long)(B_ * LQ_ * E_ / 4), SCALE);
    conv_scale_kernel<<<1024, 256, 0, stream>>>(states, sb, (long)(B_ * LK_ * D_ / 4), 1.0f);
    transpose_bf16_kernel<<<dim3(4, 16, 32), dim3(32, 8), 0, stream>>>(
        Wk, wkt, D_, E_, (long)D_ * E_, (long)D_ * E_);
    transpose_bf16_kernel<<<dim3(4, 16, 32), dim3(32, 8), 0, stream>>>(
        Wv, wvt, D_, E_, (long)D_ * E_, (long)D_ * E_);
    transpose_bf16_kernel<<<dim3(4, 128, 1), dim3(32, 8), 0, stream>>>(
        Wo, wot, H_ * E_, E_, 0L, 0L);

    kv_proj_kernel<<<2048, 512, 0, stream>>>(sb, wkt, wvt, bk, bv, Kb, Vtb);
    attn_kernel<<<2048, 256, 0, stream>>>(qb, Kb, Vtb, ctx);

    init_out_kernel<<<1024, 256, 0, stream>>>(out, bo);
    out_proj_kernel<<<dim3(64, 8), 256, 0, stream>>>(ctx, wot, out);
}

// Round 8
// 386.130 us; speedup vs baseline: 1.4546x; 1.0315x over previous
//
#include <hip/hip_runtime.h>

#define H_  32
#define E_  128
#define D_  512
#define B_  8
#define LQ_ 1024
#define LK_ 1024

typedef __bf16 bf16x8 __attribute__((ext_vector_type(8)));
typedef float  f32x4  __attribute__((ext_vector_type(4)));
typedef float  f32x16 __attribute__((ext_vector_type(16)));

typedef __attribute__((address_space(1))) const unsigned int guint;
typedef __attribute__((address_space(3))) unsigned int luint;

__device__ __forceinline__ f32x4 MFMA16(bf16x8 a, bf16x8 b, f32x4 c) {
    return __builtin_amdgcn_mfma_f32_16x16x32_bf16(a, b, c, 0, 0, 0);
}
__device__ __forceinline__ f32x16 MFMA32(bf16x8 a, bf16x8 b, f32x16 c) {
    return __builtin_amdgcn_mfma_f32_32x32x16_bf16(a, b, c, 0, 0, 0);
}

__device__ __forceinline__ unsigned short f2bf(float x) {  // RNE
    union { float f; unsigned u; } v; v.f = x;
    unsigned r = v.u + 0x7fffu + ((v.u >> 16) & 1u);
    return (unsigned short)(r >> 16);
}
// pack two fp32 -> bf16x2 via byte-perm (truncating; P in [0,~32], bias ~2^-9: fine)
__device__ __forceinline__ unsigned pkbf(float a, float b) {
    union { float f; unsigned u; } x, y; x.f = a; y.f = b;
    return __builtin_amdgcn_perm(y.u, x.u, 0x07060302u);
}

// ---------------------------------------------------------------- converts
__global__ void conv_scale_kernel(const float* __restrict__ in,
                                  unsigned short* __restrict__ out,
                                  long n4, float scale) {
    long i = blockIdx.x * (long)blockDim.x + threadIdx.x;
    long stride = (long)gridDim.x * blockDim.x;
    for (; i < n4; i += stride) {
        float4 v = ((const float4*)in)[i];
        union { unsigned long long u; unsigned short s[4]; } p;
        p.s[0] = f2bf(v.x * scale); p.s[1] = f2bf(v.y * scale);
        p.s[2] = f2bf(v.z * scale); p.s[3] = f2bf(v.w * scale);
        ((unsigned long long*)out)[i] = p.u;
    }
}

__global__ void transpose_bf16_kernel(const float* __restrict__ in,
                                      unsigned short* __restrict__ out,
                                      int R, int C, long inStride, long outStride) {
    in  += (long)blockIdx.z * inStride;
    out += (long)blockIdx.z * outStride;
    __shared__ float t[32][33];
    int x = threadIdx.x, y = threadIdx.y;
    int c0 = blockIdx.x * 32, r0 = blockIdx.y * 32;
    for (int i = 0; i < 32; i += 8) t[y + i][x] = in[(long)(r0 + y + i) * C + (c0 + x)];
    __syncthreads();
    for (int i = 0; i < 32; i += 8)
        out[(long)(c0 + y + i) * R + (r0 + x)] = f2bf(t[x][y + i]);
}

// ---------------------------------------------------------------- KV projection
// (byte-identical to round 6 — verified) 256x128 tile, BK=32, global_load_lds
// staging into linear chunk-swizzled LDS, double-buffered, 48 KB, no setprio.
__global__ __launch_bounds__(512, 4) void kv_proj_kernel(
    const unsigned short* __restrict__ sb,   // [B][LK][D] bf16
    const unsigned short* __restrict__ wkt,  // [H][E][D]  bf16 (Wk^T)
    const unsigned short* __restrict__ wvt,  // [H][E][D]
    const float* __restrict__ bk, const float* __restrict__ bv,
    unsigned short* __restrict__ Kb,         // [H][B][LK][E]
    unsigned short* __restrict__ Vtb)        // [H][B][E][LK]
{
    int bid = blockIdx.x;
    const int x = bid & 7;  int s = bid >> 3;
    const int mt = s & 3;   s >>= 2;
    const int b  = s & 7;   s >>= 3;
    const int kv = s & 1;   s >>= 1;
    const int h  = s * 8 + x;                // XCD hint: h&7 = XCD

    const unsigned short* wt = kv ? wvt : wkt;
    const float* bias = kv ? bv : bk;

    __shared__ unsigned short As[2][256 * 32];   // linear, chunk-swizzled
    __shared__ unsigned short Bs[2][128 * 32];

    const int tid = threadIdx.x;
    const int wave = tid >> 6, lane = tid & 63;
    const int ln = lane & 31, hi = lane >> 5;
    const int wm = wave & 3, wn = wave >> 2;

    const unsigned short* Ag = sb + ((long)b * LK_ + mt * 256) * D_;
    const unsigned short* Bg = wt + (long)h * E_ * D_;

    int aoff[2], boff;
    #pragma unroll
    for (int d = 0; d < 2; d++) {
        int row = (wave * 2 + d) * 16 + (lane >> 2);
        int ch  = (lane & 3) ^ ((row >> 1) & 3);
        aoff[d] = row * D_ + ch * 8;
    }
    {
        int row = wave * 16 + (lane >> 2);
        int ch  = (lane & 3) ^ ((row >> 1) & 3);
        boff = row * D_ + ch * 8;
    }

    #define KV_STAGE(d0_, buf_)                                                     \
        do {                                                                        \
            _Pragma("unroll")                                                       \
            for (int d = 0; d < 2; d++)                                             \
                __builtin_amdgcn_global_load_lds(                                   \
                    (guint*)(Ag + aoff[d] + (d0_)),                                 \
                    (luint*)&As[buf_][(wave * 2 + d) * 512], 16, 0, 0);             \
            __builtin_amdgcn_global_load_lds(                                       \
                (guint*)(Bg + boff + (d0_)),                                        \
                (luint*)&Bs[buf_][wave * 512], 16, 0, 0);                           \
        } while (0)

    KV_STAGE(0, 0);
    __syncthreads();

    f32x16 acc[4] = {};   // [mb][nb] 2x2

    for (int it = 0; it < 16; it++) {
        const int buf = it & 1;
        if (it < 15) KV_STAGE((it + 1) * 32, buf ^ 1);

        #pragma unroll
        for (int ss = 0; ss < 2; ss++) {
            const int c = ss * 2 + hi;                 // chunk index (8 elems)
            bf16x8 af[2], bfr[2];
            #pragma unroll
            for (int mb = 0; mb < 2; mb++) {
                const int r = wm * 64 + mb * 32 + ln;
                af[mb] = *(const bf16x8*)&As[buf][r * 32 + (c ^ ((r >> 1) & 3)) * 8];
            }
            #pragma unroll
            for (int nb = 0; nb < 2; nb++) {
                const int r = wn * 64 + nb * 32 + ln;
                bfr[nb] = *(const bf16x8*)&Bs[buf][r * 32 + (c ^ ((r >> 1) & 3)) * 8];
            }
            #pragma unroll
            for (int mb = 0; mb < 2; mb++)
                #pragma unroll
                for (int nb = 0; nb < 2; nb++)
                    acc[mb * 2 + nb] = MFMA32(af[mb], bfr[nb], acc[mb * 2 + nb]);
        }
        __syncthreads();                               // drains DMAs; joins waves
    }

    const int row0 = mt * 256 + wm * 64;
    const int e0 = wn * 64;
    if (!kv) {
        const long base = ((long)h * B_ + b) * LK_;
        #pragma unroll
        for (int mb = 0; mb < 2; mb++)
            #pragma unroll
            for (int nb = 0; nb < 2; nb++) {
                const int e = e0 + nb * 32 + ln;
                const float be = bias[h * E_ + e];
                #pragma unroll
                for (int r = 0; r < 16; r++) {
                    int row = row0 + mb * 32 + (r & 3) + 8 * (r >> 2) + 4 * hi;
                    Kb[(base + row) * E_ + e] = f2bf(acc[mb * 2 + nb][r] + be);
                }
            }
    } else {
        const long vbase = ((long)h * B_ + b) * E_;
        #pragma unroll
        for (int mb = 0; mb < 2; mb++)
            #pragma unroll
            for (int nb = 0; nb < 2; nb++) {
                const int e = e0 + nb * 32 + ln;
                const float be = bias[h * E_ + e];
                #pragma unroll
                for (int rg = 0; rg < 4; rg++) {
                    int k0 = row0 + mb * 32 + 8 * rg + 4 * hi;
                    union { unsigned long long u; unsigned short s2[4]; } pk;
                    #pragma unroll
                    for (int j = 0; j < 4; j++)
                        pk.s2[j] = f2bf(acc[mb * 2 + nb][rg * 4 + j] + be);
                    *(unsigned long long*)&Vtb[(vbase + e) * (long)LK_ + k0] = pk.u;
                }
            }
    }
}

// ---------------------------------------------------------------- flash attention
// (byte-identical to round 6 / round 2 — verified 173 us, 78 MB fetch)
// DO NOT add s_setprio: it desyncs qt-sibling blocks' K/V reuse and thrashes L3.
__global__ __launch_bounds__(256, 3) void attn_kernel(
    const unsigned short* __restrict__ qb,   // [B][LQ][E] bf16, scale*log2e folded
    const unsigned short* __restrict__ Kb,   // [H][B][LK][E]
    const unsigned short* __restrict__ Vtb,  // [H][B][E][LK]
    unsigned short* __restrict__ ctx)        // [B][LQ][H*E] bf16
{
    int bid = blockIdx.x;
    const int b = bid & 7;                   // XCD hint
    int s = bid >> 3;
    const int qt = s & 7;
    const int h  = s >> 3;

    __shared__ unsigned short Ks[64 * 128];      // swizzled: slot c holds chunk c^(row&15)
    __shared__ unsigned short Vs[2][128 * 64];   // swizzled: slot c holds chunk c^(row&7)

    const int tid = threadIdx.x;
    const int wave = tid >> 6, lane = tid & 63;
    const int ln = lane & 31, hi = lane >> 5;

    const unsigned short* Kg = Kb  + ((long)h * B_ + b) * (long)LK_ * E_;
    const unsigned short* Vg = Vtb + ((long)h * B_ + b) * (long)E_ * LK_;
    const int qrow = qt * 128 + wave * 32;

    // Q B-frags in registers: B[n=q=ln][k = es*16 + 8*hi + j]
    bf16x8 qf[8];
    #pragma unroll
    for (int s8 = 0; s8 < 8; s8++) {
        union { uint4 u; bf16x8 v; } t;
        t.u = *(const uint4*)&qb[((long)b * LQ_ + qrow + ln) * E_ + s8 * 16 + hi * 8];
        qf[s8] = t.v;
    }

    int koff[4], voff[4];
    #pragma unroll
    for (int d = 0; d < 4; d++) {
        int krow = (wave * 4 + d) * 4 + (lane >> 4);          // 0..63
        int kc = (lane & 15) ^ (krow & 15);
        koff[d] = krow * E_ + kc * 8;
        int vrow = (wave * 4 + d) * 8 + (lane >> 3);          // 0..127 (e)
        int vc = (lane & 7) ^ (vrow & 7);
        voff[d] = vrow * LK_ + vc * 8;
    }

    #define STAGE_K(t_)                                                             \
        do {                                                                        \
            _Pragma("unroll")                                                       \
            for (int d = 0; d < 4; d++)                                             \
                __builtin_amdgcn_global_load_lds(                                   \
                    (guint*)(Kg + (long)(t_) * (64 * E_) + koff[d]),                \
                    (luint*)&Ks[(wave * 4 + d) * 512], 16, 0, 0);                   \
        } while (0)
    #define STAGE_V(t_, buf_)                                                       \
        do {                                                                        \
            _Pragma("unroll")                                                       \
            for (int d = 0; d < 4; d++)                                             \
                __builtin_amdgcn_global_load_lds(                                   \
                    (guint*)(Vg + (t_) * 64 + voff[d]),                             \
                    (luint*)&Vs[buf_][(wave * 4 + d) * 512], 16, 0, 0);             \
        } while (0)

    STAGE_K(0);
    STAGE_V(0, 0);
    __syncthreads();

    f32x16 O[4] = {};
    float l_run = 0.f;

    for (int t = 0; t < 16; t++) {
        const int vb = t & 1;

        // S^T = K · Q^T : 2 m-blocks of 32 k, q = ln
        f32x16 S[2] = {};
        #pragma unroll
        for (int es = 0; es < 8; es++) {
            #pragma unroll
            for (int mb = 0; mb < 2; mb++) {
                const int row = mb * 32 + ln;
                const int cs = (es * 2 + hi) ^ (row & 15);
                bf16x8 kf = *(const bf16x8*)&Ks[row * 128 + cs * 8];
                S[mb] = MFMA32(kf, qf[es], S[mb]);
            }
        }

        __syncthreads();                       // A: all waves done reading Ks
        if (t < 15) {
            STAGE_K(t + 1);                    // overwrite Ks (async)
            STAGE_V(t + 1, vb ^ 1);            // fill other V buffer (async)
        }

        float tsum = 0.f;
        #pragma unroll
        for (int mb = 0; mb < 2; mb++) {
            float pv[16];
            #pragma unroll
            for (int r = 0; r < 16; r++) {
                pv[r] = __builtin_amdgcn_exp2f(S[mb][r]);
                tsum += pv[r];
            }
            unsigned a0 = pkbf(pv[0],  pv[1]),  b0 = pkbf(pv[2],  pv[3]);
            unsigned a1 = pkbf(pv[4],  pv[5]),  b1 = pkbf(pv[6],  pv[7]);
            unsigned a2 = pkbf(pv[8],  pv[9]),  b2 = pkbf(pv[10], pv[11]);
            unsigned a3 = pkbf(pv[12], pv[13]), b3 = pkbf(pv[14], pv[15]);
            unsigned r0 = __shfl_xor(hi ? a0 : a1, 32, 64);
            unsigned r1 = __shfl_xor(hi ? b0 : b1, 32, 64);
            unsigned r2 = __shfl_xor(hi ? a2 : a3, 32, 64);
            unsigned r3 = __shfl_xor(hi ? b2 : b3, 32, 64);
            #pragma unroll
            for (int st = 0; st < 2; st++) {
                union { unsigned u[4]; bf16x8 v; } pa;
                if (st == 0) {
                    pa.u[0] = hi ? r0 : a0;  pa.u[1] = hi ? r1 : b0;
                    pa.u[2] = hi ? a1 : r0;  pa.u[3] = hi ? b1 : r1;
                } else {
                    pa.u[0] = hi ? r2 : a2;  pa.u[1] = hi ? r3 : b2;
                    pa.u[2] = hi ? a3 : r2;  pa.u[3] = hi ? b3 : r3;
                }
                #pragma unroll
                for (int nb = 0; nb < 4; nb++) {
                    const int vrow = nb * 32 + ln;
                    const int vc = (mb * 4 + st * 2 + hi) ^ (vrow & 7);
                    bf16x8 vf = *(const bf16x8*)&Vs[vb][vrow * 64 + vc * 8];
                    O[nb] = MFMA32(pa.v, vf, O[nb]);
                }
            }
        }
        tsum += __shfl_xor(tsum, 32, 64);
        l_run += tsum;

        __syncthreads();                       // B: drains DMAs -> K(t+1), V(t+1) landed
    }

    const float linv = 1.f / l_run;          // lane ln holds l for q = ln
    #pragma unroll
    for (int r = 0; r < 16; r++) {
        const int rowmap = (r & 3) + 8 * (r >> 2) + 4 * hi;
        float lv = __shfl(linv, rowmap, 64);
        int qg = qrow + rowmap;
        long rowbase = ((long)b * LQ_ + qg) * (H_ * E_) + h * E_;
        #pragma unroll
        for (int nb = 0; nb < 4; nb++)
            ctx[rowbase + nb * 32 + ln] = f2bf(O[nb][r] * lv);
    }
}

// ---------------------------------------------------------------- output projection
// Round-8: atomic-free full-K streaming GEMM (round-7 design, dest bugs fixed).
// Grid 256 blocks (32 ctx rows each), 512 threads (8 waves = 2m x 4n).
// K=4096 in 32 chunks of 128; double-buffered global_load_lds (As 2x8KB +
// Bs 2x32KB = 80 KB). Each 1KB DMA covers 4 rows x 128 elems = 512 ELEMENTS:
// LDS dest is the WAVE-UNIFORM base dd*512 (HW adds lane*16B); the per-lane
// layout lives in the global source offset only (rule #21 / m104 lesson —
// round-7 bug: per-lane dest + dd*1024 stride corrupted LDS).
// Swizzle: slot s of row r holds chunk s^(r&7); read chunk c at slot c^(r&7).
// Epilogue: out = acc + bo, written exactly once (no atomics, no init pass).
__global__ __launch_bounds__(512) void out_proj_kernel(
    const unsigned short* __restrict__ ctx,  // [B*LQ][H*E] bf16
    const unsigned short* __restrict__ wot,  // [E][H*E] bf16 (Wo^T)
    const float* __restrict__ bo,            // [E]
    float* __restrict__ out)                 // [B*LQ][E] fp32
{
    const int qt = blockIdx.x;               // 32-row slab of ctx/out
    __shared__ unsigned short As[2][32 * 128];
    __shared__ unsigned short Bs[2][128 * 128];

    const int tid = threadIdx.x;
    const int wave = tid >> 6, lane = tid & 63;
    const int l16 = lane & 15, l4 = lane >> 4;
    const int wm = wave >> 2, wn = wave & 3;

    const unsigned short* Ag = ctx + (long)(qt * 32) * (H_ * E_);

    // 40 DMAs/chunk, 5 per wave: d = wave*5+i; d<8 -> A-tile (dd=d), else B-tile
    // (dd=d-8). Lane covers row r = dd*4 + l4, slot l16, source chunk l16^(r&7).
    long goff[5]; int isB[5], dbase[5];
    #pragma unroll
    for (int i = 0; i < 5; i++) {
        int d  = wave * 5 + i;
        int bB = (d >= 8);
        int dd = bB ? d - 8 : d;
        int r  = dd * 4 + l4;
        int sc = l16 ^ (r & 7);
        goff[i]  = (long)r * (H_ * E_) + sc * 8;   // both ctx and wot rows stride 4096
        isB[i]   = bB;
        dbase[i] = dd * 512;                       // wave-uniform LDS element base
    }

    #define OP_STAGE(k0_, buf_)                                                     \
        do {                                                                        \
            _Pragma("unroll")                                                       \
            for (int i = 0; i < 5; i++) {                                           \
                if (isB[i])                                                         \
                    __builtin_amdgcn_global_load_lds(                               \
                        (guint*)(wot + goff[i] + (k0_)),                            \
                        (luint*)&Bs[buf_][dbase[i]], 16, 0, 0);                     \
                else                                                                \
                    __builtin_amdgcn_global_load_lds(                               \
                        (guint*)(Ag + goff[i] + (k0_)),                             \
                        (luint*)&As[buf_][dbase[i]], 16, 0, 0);                     \
            }                                                                       \
        } while (0)

    OP_STAGE(0, 0);
    __syncthreads();

    f32x4 acc[2] = {};

    for (int kt = 0; kt < 32; kt++) {
        const int buf = kt & 1;
        if (kt < 31) OP_STAGE((kt + 1) * 128, buf ^ 1);

        const int ar = wm * 16 + l16;                 // A row (m), row = 128 elems
        #pragma unroll
        for (int ks = 0; ks < 4; ks++) {
            const int sl = ks * 4 + l4;               // logical 16B slot (k)
            bf16x8 af = *(const bf16x8*)&As[buf][ar * 128 + (sl ^ (ar & 7)) * 8];
            #pragma unroll
            for (int nb = 0; nb < 2; nb++) {
                const int br = wn * 32 + nb * 16 + l16;   // B row (e)
                bf16x8 bf = *(const bf16x8*)&Bs[buf][br * 128 + (sl ^ (br & 7)) * 8];
                acc[nb] = MFMA16(af, bf, acc[nb]);
            }
        }
        __syncthreads();
    }

    #pragma unroll
    for (int nb = 0; nb < 2; nb++) {
        const int e = wn * 32 + nb * 16 + l16;
        const float be = bo[e];
        #pragma unroll
        for (int r = 0; r < 4; r++) {
            int m = qt * 32 + wm * 16 + l4 * 4 + r;
            out[(long)m * E_ + e] = acc[nb][r] + be;
        }
    }
}

// ---------------------------------------------------------------- launcher
extern "C" void kernel_launch(void* const* d_in, const int* in_sizes, int n_in,
                              void* d_out, int out_size, void* d_ws, size_t ws_size,
                              hipStream_t stream) {
    const float* query  = (const float*)d_in[0];
    const float* states = (const float*)d_in[1];
    const float* Wk     = (const float*)d_in[2];
    const float* bk     = (const float*)d_in[3];
    const float* Wv     = (const float*)d_in[4];
    const float* bv     = (const float*)d_in[5];
    const float* Wo     = (const float*)d_in[6];
    const float* bo     = (const float*)d_in[7];
    float* out = (float*)d_out;

    const size_t WS_QB  = 0;
    const size_t WS_SB  = WS_QB  + 2097152UL;
    const size_t WS_WKT = WS_SB  + 8388608UL;
    const size_t WS_WVT = WS_WKT + 4194304UL;
    const size_t WS_WOT = WS_WVT + 4194304UL;
    const size_t WS_KB  = WS_WOT + 1048576UL;
    const size_t WS_VTB = WS_KB  + 67108864UL;
    const size_t WS_CTX = WS_VTB + 67108864UL;
    const size_t WS_END = WS_CTX + 67108864UL;
    if (ws_size < WS_END) return;

    char* ws = (char*)d_ws;
    unsigned short* qb  = (unsigned short*)(ws + WS_QB);
    unsigned short* sb  = (unsigned short*)(ws + WS_SB);
    unsigned short* wkt = (unsigned short*)(ws + WS_WKT);
    unsigned short* wvt = (unsigned short*)(ws + WS_WVT);
    unsigned short* wot = (unsigned short*)(ws + WS_WOT);
    unsigned short* Kb  = (unsigned short*)(ws + WS_KB);
    unsigned short* Vtb = (unsigned short*)(ws + WS_VTB);
    unsigned short* ctx = (unsigned short*)(ws + WS_CTX);

    // 1/sqrt(E) * log2(e) — attention softmax runs in base-2 domain
    const float SCALE = 0.12751744f;

    conv_scale_kernel<<<512, 256, 0, stream>>>(query, qb, (long)(B_ * LQ_ * E_ / 4), SCALE);
    conv_scale_kernel<<<1024, 256, 0, stream>>>(states, sb, (long)(B_ * LK_ * D_ / 4), 1.0f);
    transpose_bf16_kernel<<<dim3(4, 16, 32), dim3(32, 8), 0, stream>>>(
        Wk, wkt, D_, E_, (long)D_ * E_, (long)D_ * E_);
    transpose_bf16_kernel<<<dim3(4, 16, 32), dim3(32, 8), 0, stream>>>(
        Wv, wvt, D_, E_, (long)D_ * E_, (long)D_ * E_);
    transpose_bf16_kernel<<<dim3(4, 128, 1), dim3(32, 8), 0, stream>>>(
        Wo, wot, H_ * E_, E_, 0L, 0L);

    kv_proj_kernel<<<2048, 512, 0, stream>>>(sb, wkt, wvt, bk, bv, Kb, Vtb);
    attn_kernel<<<2048, 256, 0, stream>>>(qb, Kb, Vtb, ctx);

    out_proj_kernel<<<256, 512, 0, stream>>>(ctx, wot, bo, out);
}